// Round 6
// baseline (208.052 us; speedup 1.0000x reference)
//
#include <hip/hip_runtime.h>
#include <hip/hip_bf16.h>
#include <stdint.h>

typedef __bf16 bf16;
typedef __bf16 bf16x8 __attribute__((ext_vector_type(8)));
typedef float f32x4 __attribute__((ext_vector_type(4)));
typedef float f32x16 __attribute__((ext_vector_type(16)));

#define BATCH 4
#define SEQ   2048
#define DIM   1024
#define NH    16
#define HD    64

// Q projection pre-scaled by (1/sqrt(HD)) * log2(e): softmax runs in exp2 domain.
#define QSCALE 0.18033688011112042f  // 0.125 * 1.4426950408889634

#define MFMA(a, b, c)   __builtin_amdgcn_mfma_f32_16x16x32_bf16((a), (b), (c), 0, 0, 0)
#define MFMA32(a, b, c) __builtin_amdgcn_mfma_f32_32x32x16_bf16((a), (b), (c), 0, 0, 0)

// global -> LDS direct copy, 16B per lane. LDS dest is wave-uniform base+lane*16.
#define GLOAD16(gsrc, ldst)                                                        \
  __builtin_amdgcn_global_load_lds(                                                \
      (__attribute__((address_space(1))) unsigned int*)(void*)(gsrc),              \
      (__attribute__((address_space(3))) unsigned int*)(ldst), 16, 0, 0)

static __device__ __forceinline__ float fast_exp2(float x) {
#if __has_builtin(__builtin_amdgcn_exp2f)
  return __builtin_amdgcn_exp2f(x);
#else
  return exp2f(x);
#endif
}

// ---------------------------------------------------------------------------
// Weight conversion: f32 -> bf16, 4 tensors of DIM*DIM each.
// ---------------------------------------------------------------------------
__global__ __launch_bounds__(256) void cvt_w_kernel(
    const float* __restrict__ w0, const float* __restrict__ w1,
    const float* __restrict__ w2, const float* __restrict__ w3,
    bf16* __restrict__ o0, bf16* __restrict__ o1,
    bf16* __restrict__ o2, bf16* __restrict__ o3) {
  const float* s;
  bf16* d;
  switch (blockIdx.y) {
    case 0: s = w0; d = o0; break;
    case 1: s = w1; d = o1; break;
    case 2: s = w2; d = o2; break;
    default: s = w3; d = o3; break;
  }
  const int i = (blockIdx.x * 256 + threadIdx.x) * 4;
  const float4 v = *(const float4*)(s + i);
  ushort4 o;
  o.x = __builtin_bit_cast(unsigned short, (bf16)v.x);
  o.y = __builtin_bit_cast(unsigned short, (bf16)v.y);
  o.z = __builtin_bit_cast(unsigned short, (bf16)v.z);
  o.w = __builtin_bit_cast(unsigned short, (bf16)v.w);
  *(ushort4*)((unsigned short*)d + i) = o;
}

// ---------------------------------------------------------------------------
// Activation conversion: f32 -> bf16, BATCH*SEQ*DIM elements, 8/thread.
// ---------------------------------------------------------------------------
__global__ __launch_bounds__(256) void cvt_x_kernel(
    const float* __restrict__ in, bf16* __restrict__ out) {
  const int i = (blockIdx.x * 256 + threadIdx.x) * 8;
  const float4 v0 = *(const float4*)(in + i);
  const float4 v1 = *(const float4*)(in + i + 4);
  bf16x8 p;
  p[0] = (bf16)v0.x; p[1] = (bf16)v0.y; p[2] = (bf16)v0.z; p[3] = (bf16)v0.w;
  p[4] = (bf16)v1.x; p[5] = (bf16)v1.y; p[6] = (bf16)v1.z; p[7] = (bf16)v1.w;
  *(bf16x8*)(out + i) = p;
}

// ---------------------------------------------------------------------------
// Projection GEMM (pure bf16, out_gemm structure): C = A·W^T + bias.
// A: bf16 [8192,1024] (pre-converted activations), W: bf16 [1024,1024].
// BK=64, double-buffered LDS, ONE barrier per K-step, both operands GLOAD16,
// 128B rows with (row&7)<<4 XOR swizzle (0 conflicts, verified),
// XCD-chunked block swizzle.
// z=0: out = bf16(C * QSCALE) (Q) | z=1: bf16(C) (K) | z=2: Vt transposed.
// ---------------------------------------------------------------------------
__global__ __launch_bounds__(256, 2) void proj_gemm(
    const bf16* __restrict__ A, const bf16* __restrict__ W,
    const float* __restrict__ bias, bf16* __restrict__ out, int z) {
  __shared__ bf16 Ab[2][128 * 64];
  __shared__ bf16 Bb[2][128 * 64];

  const int tid  = threadIdx.x;
  const int wave = tid >> 6, lane = tid & 63;
  const int r = lane & 15, g = lane >> 4;

  const int wg = blockIdx.x;
  const int sw = ((wg & 7) << 6) | (wg >> 3);
  const int m0 = (sw >> 3) * 128, n0 = (sw & 7) * 128;
  const int wm = (wave >> 1) * 64, wn = (wave & 1) * 64;

  f32x4 acc[4][4] = {};

  const int srr = lane >> 3;
  const int scb = (lane & 7) * 16;
  const int swz = srr << 4;

#define STAGEP(buf, k0)                                                             \
  do {                                                                              \
    _Pragma("unroll") for (int i_ = 0; i_ < 4; ++i_) {                              \
      const int row_ = wave * 32 + i_ * 8 + srr;                                    \
      const char* as_ =                                                             \
          (const char*)(A + (size_t)(m0 + row_) * DIM + (k0)) + (scb ^ swz);        \
      GLOAD16(as_, (char*)&Ab[buf][0] + (wave * 32 + i_ * 8) * 128);                \
      const char* bs_ =                                                             \
          (const char*)(W + (size_t)(n0 + row_) * DIM + (k0)) + (scb ^ swz);        \
      GLOAD16(bs_, (char*)&Bb[buf][0] + (wave * 32 + i_ * 8) * 128);                \
    }                                                                               \
  } while (0)

  STAGEP(0, 0);
  __syncthreads();

  const int NK = DIM / 64;
  for (int it = 0; it < NK; ++it) {
    const int cur = it & 1;
    if (it + 1 < NK) STAGEP(cur ^ 1, (it + 1) * 64);

#pragma unroll
    for (int ks = 0; ks < 2; ++ks) {
      bf16x8 af[4], bfr[4];
#pragma unroll
      for (int mt = 0; mt < 4; ++mt) {
        const int mr = wm + mt * 16 + r;
        af[mt] = *(bf16x8*)((char*)&Ab[cur][0] + mr * 128 +
                            ((ks * 64 + g * 16) ^ ((mr & 7) << 4)));
      }
#pragma unroll
      for (int nt = 0; nt < 4; ++nt) {
        const int nr = wn + nt * 16 + r;
        bfr[nt] = *(bf16x8*)((char*)&Bb[cur][0] + nr * 128 +
                             ((ks * 64 + g * 16) ^ ((nr & 7) << 4)));
      }
#pragma unroll
      for (int mt = 0; mt < 4; ++mt)
#pragma unroll
        for (int nt = 0; nt < 4; ++nt)
          acc[mt][nt] = MFMA(af[mt], bfr[nt], acc[mt][nt]);
    }

    __syncthreads();
  }
#undef STAGEP

  // --- epilogue ---  C/D layout: row = g*4 + i, col = r (per 16x16 tile)
  if (z == 2) {
#pragma unroll
    for (int nt = 0; nt < 4; ++nt) {
      const int n = n0 + wn + nt * 16 + r;
      const float bn = bias[n];
#pragma unroll
      for (int mt = 0; mt < 4; ++mt) {
        const int m = m0 + wm + mt * 16 + g * 4;
        const int b = m >> 11, t = m & 2047;
        ushort4 pk;
        pk.x = __builtin_bit_cast(unsigned short, (bf16)(acc[mt][nt][0] + bn));
        pk.y = __builtin_bit_cast(unsigned short, (bf16)(acc[mt][nt][1] + bn));
        pk.z = __builtin_bit_cast(unsigned short, (bf16)(acc[mt][nt][2] + bn));
        pk.w = __builtin_bit_cast(unsigned short, (bf16)(acc[mt][nt][3] + bn));
        *(ushort4*)((unsigned short*)out + (((size_t)(b * DIM + n)) << 11) + t) = pk;
      }
    }
  } else {
    const float scale = (z == 0) ? QSCALE : 1.0f;
#pragma unroll
    for (int mt = 0; mt < 4; ++mt)
#pragma unroll
      for (int nt = 0; nt < 4; ++nt) {
        const int n = n0 + wn + nt * 16 + r;
        const float bn = bias[n];
#pragma unroll
        for (int i = 0; i < 4; ++i) {
          const int m = m0 + wm + mt * 16 + g * 4 + i;
          out[(size_t)m * DIM + n] = (bf16)((acc[mt][nt][i] + bn) * scale);
        }
      }
  }
}

// ---------------------------------------------------------------------------
// Fused attention, 32x32 swapped structure (unchanged from R5 — verified).
// ---------------------------------------------------------------------------
__global__ __launch_bounds__(256, 4) void attn_kernel(
    const bf16* __restrict__ Q, const bf16* __restrict__ K,
    const bf16* __restrict__ Vt, bf16* __restrict__ ctx) {
  __shared__ bf16 Kb[2][64 * 64];   // [kv 64][d 64], 128B rows, XOR-swizzled
  __shared__ bf16 Vb[2][64 * 64];   // [d 64][kv 64], 128B rows, XOR-swizzled

  const int tid  = threadIdx.x;
  const int wave = tid >> 6, lane = tid & 63;
  const int l31 = lane & 31, hi = lane >> 5;

  const int wg  = blockIdx.x;
  const int swb = (wg & 7) * 128 + (wg >> 3);
  const int qblk = swb & 15, bh = swb >> 4;
  const int b = bh >> 4, h = bh & 15;
  const int q0 = qblk * 128 + wave * 32;

  bf16x8 qf[4];
  {
    const bf16* qp = Q + ((size_t)(b * SEQ + q0 + l31) * DIM + h * HD);
#pragma unroll
    for (int st = 0; st < 4; ++st)
      qf[st] = *(const bf16x8*)(qp + st * 16 + hi * 8);
  }

  f32x16 accO[2] = {};
  float m_i = -3e38f, l_i = 0.0f;

  const bf16* Kbase = K + (size_t)(b * SEQ) * DIM + h * HD;
  const bf16* Vbase = Vt + (size_t)(b * DIM + h * HD) * SEQ;

  const int srr = lane >> 3;
  const int scb = (lane & 7) * 16;
  const int swz = srr << 4;

  int koff[2], voff[2], kdst[2], vdst[2];
#pragma unroll
  for (int i = 0; i < 2; ++i) {
    const int rl = wave * 16 + i * 8 + srr;
    const int r32 = rl & 31;
    const int t = (r32 >> 2) & 3;
    const int rsrc = (rl & 32) + ((t == 1 || t == 2) ? (r32 ^ 12) : r32);
    koff[i] = rsrc * (DIM * 2) + (scb ^ swz);
    voff[i] = rl * (SEQ * 2) + (scb ^ swz);
    kdst[i] = (wave * 16 + i * 8) * 128;
    vdst[i] = (wave * 16 + i * 8) * 128;
  }

#define STAGE(buf, kv0)                                                             \
  do {                                                                              \
    _Pragma("unroll") for (int i_ = 0; i_ < 2; ++i_) {                              \
      GLOAD16((const char*)Kbase + (size_t)(kv0) * (DIM * 2) + koff[i_],            \
              (char*)&Kb[buf][0] + kdst[i_]);                                       \
      GLOAD16((const char*)Vbase + (size_t)(kv0) * 2 + voff[i_],                    \
              (char*)&Vb[buf][0] + vdst[i_]);                                       \
    }                                                                               \
  } while (0)

  STAGE(0, 0);
  __syncthreads();

  const int NIT = SEQ / 64;
  for (int it = 0; it < NIT; ++it) {
    const int cur = it & 1;
    if (it + 1 < NIT) STAGE(cur ^ 1, (it + 1) * 64);

    f32x16 s[2] = {};
    __builtin_amdgcn_s_setprio(1);
#pragma unroll
    for (int kvt = 0; kvt < 2; ++kvt) {
      const int row = kvt * 32 + l31;
      const char* kb = (const char*)&Kb[cur][0] + row * 128;
      const int rsw = (row & 7) << 4;
#pragma unroll
      for (int st = 0; st < 4; ++st) {
        const bf16x8 kf = *(const bf16x8*)(kb + ((st * 32 + hi * 16) ^ rsw));
        s[kvt] = MFMA32(kf, qf[st], s[kvt]);
      }
    }
    __builtin_amdgcn_s_setprio(0);

    float pm = s[0][0];
#pragma unroll
    for (int kvt = 0; kvt < 2; ++kvt)
#pragma unroll
      for (int e = 0; e < 16; ++e)
        if (kvt || e) pm = fmaxf(pm, s[kvt][e]);
    pm = fmaxf(pm, __shfl_xor(pm, 32));

    if (__any(pm > m_i + 8.0f)) {
      const float mn = fmaxf(m_i, pm);
      const float alpha = fast_exp2(m_i - mn);
      m_i = mn;
      l_i *= alpha;
#pragma unroll
      for (int dt = 0; dt < 2; ++dt)
#pragma unroll
        for (int e = 0; e < 16; ++e) accO[dt][e] *= alpha;
    }

    float rs = 0.0f;
#pragma unroll
    for (int kvt = 0; kvt < 2; ++kvt)
#pragma unroll
      for (int e = 0; e < 16; ++e) {
        s[kvt][e] = fast_exp2(s[kvt][e] - m_i);
        rs += s[kvt][e];
      }
    l_i += rs + __shfl_xor(rs, 32);

    bf16x8 pa[2][2];
#pragma unroll
    for (int kvt = 0; kvt < 2; ++kvt)
#pragma unroll
      for (int kb = 0; kb < 2; ++kb)
#pragma unroll
        for (int j = 0; j < 8; ++j)
          pa[kvt][kb][j] = (bf16)s[kvt][kb * 8 + j];

    __builtin_amdgcn_s_setprio(1);
#pragma unroll
    for (int dt = 0; dt < 2; ++dt) {
      const int row = dt * 32 + l31;
      const char* vb = (const char*)&Vb[cur][0] + row * 128;
      const int rsw = (row & 7) << 4;
#pragma unroll
      for (int kvt = 0; kvt < 2; ++kvt)
#pragma unroll
        for (int kb = 0; kb < 2; ++kb) {
          const bf16x8 vf =
              *(const bf16x8*)(vb + ((kvt * 64 + kb * 32 + hi * 16) ^ rsw));
          accO[dt] = MFMA32(vf, pa[kvt][kb], accO[dt]);
        }
    }
    __builtin_amdgcn_s_setprio(0);

    __syncthreads();
  }
#undef STAGE

  {
    const float inv = 1.0f / l_i;
    bf16* cp = ctx + (size_t)(b * SEQ + q0 + l31) * DIM + h * HD;
#pragma unroll
    for (int dt = 0; dt < 2; ++dt)
#pragma unroll
      for (int rr = 0; rr < 4; ++rr) {
        ushort4 pk;
        pk.x = __builtin_bit_cast(unsigned short, (bf16)(accO[dt][rr * 4 + 0] * inv));
        pk.y = __builtin_bit_cast(unsigned short, (bf16)(accO[dt][rr * 4 + 1] * inv));
        pk.z = __builtin_bit_cast(unsigned short, (bf16)(accO[dt][rr * 4 + 2] * inv));
        pk.w = __builtin_bit_cast(unsigned short, (bf16)(accO[dt][rr * 4 + 3] * inv));
        *(ushort4*)(cp + dt * 32 + rr * 8 + hi * 4) = pk;
      }
  }
}

// ---------------------------------------------------------------------------
// Output GEMM (unchanged): out[m,n] = sum_k ctx[m,k] * Wo[n,k] + bo[n], f32.
// ---------------------------------------------------------------------------
__global__ __launch_bounds__(256, 2) void out_gemm(
    const bf16* __restrict__ A, const bf16* __restrict__ W,
    const float* __restrict__ bias, float* __restrict__ out) {
  __shared__ bf16 Ab[2][128 * 64];
  __shared__ bf16 Bb[2][128 * 64];

  const int tid  = threadIdx.x;
  const int wave = tid >> 6, lane = tid & 63;
  const int r = lane & 15, g = lane >> 4;

  const int wg = blockIdx.x;
  const int sw = ((wg & 7) << 6) | (wg >> 3);
  const int m0 = (sw >> 3) * 128, n0 = (sw & 7) * 128;
  const int wm = (wave >> 1) * 64, wn = (wave & 1) * 64;

  f32x4 acc[4][4] = {};

  const int srr = lane >> 3;
  const int scb = (lane & 7) * 16;
  const int swz = srr << 4;

#define STAGE2(buf, k0)                                                             \
  do {                                                                              \
    _Pragma("unroll") for (int i_ = 0; i_ < 4; ++i_) {                              \
      const int row_ = wave * 32 + i_ * 8 + srr;                                    \
      const char* as_ =                                                             \
          (const char*)(A + (size_t)(m0 + row_) * DIM + (k0)) + (scb ^ swz);        \
      GLOAD16(as_, (char*)&Ab[buf][0] + (wave * 32 + i_ * 8) * 128);                \
      const char* bs_ =                                                             \
          (const char*)(W + (size_t)(n0 + row_) * DIM + (k0)) + (scb ^ swz);        \
      GLOAD16(bs_, (char*)&Bb[buf][0] + (wave * 32 + i_ * 8) * 128);                \
    }                                                                               \
  } while (0)

  STAGE2(0, 0);
  __syncthreads();

  const int NK = DIM / 64;
  for (int it = 0; it < NK; ++it) {
    const int cur = it & 1;
    if (it + 1 < NK) STAGE2(cur ^ 1, (it + 1) * 64);

#pragma unroll
    for (int ks = 0; ks < 2; ++ks) {
      bf16x8 af[4], bfr[4];
#pragma unroll
      for (int mt = 0; mt < 4; ++mt) {
        const int mr = wm + mt * 16 + r;
        af[mt] = *(bf16x8*)((char*)&Ab[cur][0] + mr * 128 +
                            ((ks * 64 + g * 16) ^ ((mr & 7) << 4)));
      }
#pragma unroll
      for (int nt = 0; nt < 4; ++nt) {
        const int nr = wn + nt * 16 + r;
        bfr[nt] = *(bf16x8*)((char*)&Bb[cur][0] + nr * 128 +
                             ((ks * 64 + g * 16) ^ ((nr & 7) << 4)));
      }
#pragma unroll
      for (int mt = 0; mt < 4; ++mt)
#pragma unroll
        for (int nt = 0; nt < 4; ++nt)
          acc[mt][nt] = MFMA(af[mt], bfr[nt], acc[mt][nt]);
    }

    __syncthreads();
  }
#undef STAGE2

#pragma unroll
  for (int mt = 0; mt < 4; ++mt)
#pragma unroll
    for (int nt = 0; nt < 4; ++nt) {
      const int n = n0 + wn + nt * 16 + r;
      const float bn = bias[n];
#pragma unroll
      for (int i = 0; i < 4; ++i) {
        const int m = m0 + wm + mt * 16 + g * 4 + i;
        out[(size_t)m * DIM + n] = acc[mt][nt][i] + bn;
      }
    }
}

// ---------------------------------------------------------------------------
// kernel_launch
// ---------------------------------------------------------------------------
extern "C" void kernel_launch(void* const* d_in, const int* in_sizes, int n_in,
                              void* d_out, int out_size, void* d_ws, size_t ws_size,
                              hipStream_t stream) {
  const float* query  = (const float*)d_in[0];
  const float* key_in = (const float*)d_in[1];
  const float* value  = (const float*)d_in[2];
  const float* Wq = (const float*)d_in[3];
  const float* bq = (const float*)d_in[4];
  const float* Wk = (const float*)d_in[5];
  const float* bk = (const float*)d_in[6];
  const float* Wv = (const float*)d_in[7];
  const float* bv = (const float*)d_in[8];
  const float* Wo = (const float*)d_in[9];
  const float* bo = (const float*)d_in[10];

  // ws layout (72 MiB): 4 x 2MiB bf16 weights; 4 x 16MiB bf16 tensors.
  // C_b doubles as the bf16-activation staging buffer before attn runs.
  char* ws = (char*)d_ws;
  const size_t WSZ = (size_t)DIM * DIM * sizeof(bf16);
  const size_t TSZ = (size_t)BATCH * SEQ * DIM * sizeof(bf16);
  bf16* Wq_b = (bf16*)(ws);
  bf16* Wk_b = (bf16*)(ws + WSZ);
  bf16* Wv_b = (bf16*)(ws + 2 * WSZ);
  bf16* Wo_b = (bf16*)(ws + 3 * WSZ);
  bf16* Q_b  = (bf16*)(ws + 4 * WSZ);
  bf16* K_b  = (bf16*)(ws + 4 * WSZ + TSZ);
  bf16* Vt_b = (bf16*)(ws + 4 * WSZ + 2 * TSZ);
  bf16* C_b  = (bf16*)(ws + 4 * WSZ + 3 * TSZ);
  bf16* X_b  = C_b;  // staging alias: consumed before attn writes ctx

  cvt_w_kernel<<<dim3(DIM * DIM / (256 * 4), 4), 256, 0, stream>>>(
      Wq, Wk, Wv, Wo, Wq_b, Wk_b, Wv_b, Wo_b);

  const int XBLK = BATCH * SEQ * DIM / (256 * 8);  // 4096

  cvt_x_kernel<<<dim3(XBLK), 256, 0, stream>>>(query, X_b);
  proj_gemm<<<dim3(512), 256, 0, stream>>>(X_b, Wq_b, bq, Q_b, 0);

  cvt_x_kernel<<<dim3(XBLK), 256, 0, stream>>>(key_in, X_b);
  proj_gemm<<<dim3(512), 256, 0, stream>>>(X_b, Wk_b, bk, K_b, 1);

  cvt_x_kernel<<<dim3(XBLK), 256, 0, stream>>>(value, X_b);
  proj_gemm<<<dim3(512), 256, 0, stream>>>(X_b, Wv_b, bv, Vt_b, 2);

  attn_kernel<<<dim3(1024), 256, 0, stream>>>(Q_b, K_b, Vt_b, C_b);

  out_gemm<<<dim3(512), 256, 0, stream>>>(C_b, Wo_b, bo, (float*)d_out);
}